// Round 8
// baseline (192.523 us; speedup 1.0000x reference)
//
#include <hip/hip_runtime.h>
#include <stdint.h>

#define NR 8192
#define DIM 512
#define BT 256             // block tile M=N
#define BK 64              // K-tile (128 B rows, 8 x 16B chunks)
#define NT (DIM / BK)      // 8 K-tiles

typedef unsigned short u16;
typedef __attribute__((ext_vector_type(8))) __bf16 bf16x8;
typedef __attribute__((ext_vector_type(16))) float f32x16;

static __device__ __forceinline__ u16 f2bf(float f) {
    union { float f; uint32_t u; } v; v.f = f;
    uint32_t u = v.u;
    u += 0x7FFFu + ((u >> 16) & 1u);   // RNE
    return (u16)(u >> 16);
}

static __device__ __forceinline__ void gload_lds16(const void* g, void* l) {
    __builtin_amdgcn_global_load_lds(
        (__attribute__((address_space(1))) void*)(void*)g,
        (__attribute__((address_space(3))) void*)l,
        16, 0, 0);
}

static __device__ __forceinline__ uint32_t lds_addr(const void* p) {
    return (uint32_t)(uintptr_t)(__attribute__((address_space(3))) const void*)p;
}

// One block per row: reciprocal norms, exact fp32 diag term, fp32->bf16
// conversion, and zero rowsum for this call.
__global__ void prep_kernel(const float* __restrict__ xi, const float* __restrict__ xj,
                            u16* __restrict__ xib, u16* __restrict__ xjb,
                            float* __restrict__ inv_ni, float* __restrict__ inv_nj,
                            float* __restrict__ diag, float* __restrict__ rowsum) {
    const int row = blockIdx.x;
    const int t = threadIdx.x;                 // 128 threads, 4 elems each
    const float4 a = ((const float4*)(xi + (size_t)row * DIM))[t];
    const float4 b = ((const float4*)(xj + (size_t)row * DIM))[t];

    float ssi = a.x*a.x + a.y*a.y + a.z*a.z + a.w*a.w;
    float ssj = b.x*b.x + b.y*b.y + b.z*b.z + b.w*b.w;
    float dot = a.x*b.x + a.y*b.y + a.z*b.z + a.w*b.w;

    ushort4 av = { f2bf(a.x), f2bf(a.y), f2bf(a.z), f2bf(a.w) };
    ushort4 bv = { f2bf(b.x), f2bf(b.y), f2bf(b.z), f2bf(b.w) };
    ((ushort4*)(xib + (size_t)row * DIM))[t] = av;
    ((ushort4*)(xjb + (size_t)row * DIM))[t] = bv;

    #pragma unroll
    for (int m = 32; m >= 1; m >>= 1) {
        ssi += __shfl_xor(ssi, m, 64);
        ssj += __shfl_xor(ssj, m, 64);
        dot += __shfl_xor(dot, m, 64);
    }
    __shared__ float red[6];
    const int wave = t >> 6, lane = t & 63;
    if (lane == 0) { red[wave*3+0] = ssi; red[wave*3+1] = ssj; red[wave*3+2] = dot; }
    __syncthreads();
    if (t == 0) {
        float si = red[0] + red[3];
        float sj = red[1] + red[4];
        float d  = red[2] + red[5];
        float ini = rsqrtf(fmaxf(si, 1e-30f));
        float inj = rsqrtf(fmaxf(sj, 1e-30f));
        inv_ni[row] = ini;
        inv_nj[row] = inj;
        diag[row] = d * ini * inj;
        rowsum[row] = 0.0f;
    }
}

// Fused NT-GEMM + exp + row-sum.
// 256x256 tile, 1024 threads (16 waves, 4x4 of 64x64 wave tiles),
// 32x32x16 MFMA (2x2 frags, acc = 64 VGPR), BK=64, double-buffered 128 KB
// LDS, counted vmcnt(4), XOR chunk swizzle (phys = c ^ (row&7)).
// Per tile: STAGE(next buf) -> vmcnt(4) -> barrier -> {asm ds_read /
// lgkmcnt(4) / 4 MFMA} x4 k-steps pipelined -> lgkmcnt(0) -> barrier ->
// trailing MFMA. Staging hides under compute; 4 waves/SIMD TLP in-block.
__global__ __launch_bounds__(1024, 4)
void gemm_rowsum(const u16* __restrict__ A, const u16* __restrict__ B,
                 const float* __restrict__ inv_ni, const float* __restrict__ inv_nj,
                 float* __restrict__ rowsum) {
    __shared__ __align__(16) u16 lds[4][16384];   // A: [0..1], B: [2..3] by parity

    const int tid = threadIdx.x;
    // XCD-aware, L2-aware: concurrent 32 blocks/XCD = 4 row-panels x 8
    // col-panels -> A 1MB + B 2MB = 3MB < 4MB per-XCD L2.
    const int orig = blockIdx.x;            // 0..1023
    const int xcd = orig & 7, kidx = orig >> 3;   // kidx 0..127
    const int by = xcd * 4 + (kidx & 3);          // 0..31
    const int bx = kidx >> 2;                     // 0..31
    const int row0 = by * BT, col0 = bx * BT;

    // ---- staging: 2048 chunks/operand; thread t covers ci = t and t+1024 ----
    // ci -> (row = ci>>3, phys = ci&7); global logical chunk = phys ^ (row&7).
    // ci+1024 => row+128, same chunk (128 % 8 == 0) => second src = +128*DIM.
    const int st_row = tid >> 3;                        // 0..127
    const int st_lc  = (tid & 7) ^ (st_row & 7);
    const u16* gA = A + (size_t)(row0 + st_row) * DIM + st_lc * 8;
    const u16* gB = B + (size_t)(col0 + st_row) * DIM + st_lc * 8;
    char* const ldsb = (char*)&lds[0][0];
    char* const dsta = ldsb + tid * 16;                 // + p*32768 (+16384 for hi)
    char* const dstb = ldsb + 65536 + tid * 16;

    // ---- fragment reads (32x32x16): lane -> row l&31, k-half l>>5 ----
    const int lane = tid & 63;
    const int l31 = lane & 31, hh = lane >> 5, sw = lane & 7;
    const int wid = tid >> 6;
    const int wm = wid >> 2, wn = wid & 3;              // 4x4 waves, 64x64 tile
    const uint32_t ldsA32 = lds_addr(ldsb);
    const uint32_t aoff = (wm * 64 + l31) * 128;
    const uint32_t boff = (wn * 64 + l31) * 128;
    // k-step ks reads logical chunk ks*2+hh; phys = logical ^ sw
    const uint32_t cof0 = (uint32_t)(((0*2 + hh) ^ sw) * 16);
    const uint32_t cof1 = (uint32_t)(((1*2 + hh) ^ sw) * 16);
    const uint32_t cof2 = (uint32_t)(((2*2 + hh) ^ sw) * 16);
    const uint32_t cof3 = (uint32_t)(((3*2 + hh) ^ sw) * 16);

    f32x16 acc[2][2] = {};
    bf16x8 af0[2], bg0[2], af1[2], bg1[2];

#define DSR(D, ADDR) asm volatile("ds_read_b128 %0, %1" : "=v"(D) : "v"(ADDR))
#define LGKM(N) asm volatile("s_waitcnt lgkmcnt(" #N ")" ::: "memory")
#define SB0() __builtin_amdgcn_sched_barrier(0)
#define BARR() __builtin_amdgcn_s_barrier()

#define STAGE(P, TN) do {                                                      \
    gload_lds16(gA + (TN) * BK,             dsta + (P) * 32768);               \
    gload_lds16(gA + (TN) * BK + 128 * DIM, dsta + (P) * 32768 + 16384);       \
    gload_lds16(gB + (TN) * BK,             dstb + (P) * 32768);               \
    gload_lds16(gB + (TN) * BK + 128 * DIM, dstb + (P) * 32768 + 16384);       \
} while (0)

#define MM(AF, BG) do {                                                        \
    __builtin_amdgcn_s_setprio(1);                                             \
    acc[0][0] = __builtin_amdgcn_mfma_f32_32x32x16_bf16(AF[0], BG[0], acc[0][0], 0, 0, 0); \
    acc[0][1] = __builtin_amdgcn_mfma_f32_32x32x16_bf16(AF[0], BG[1], acc[0][1], 0, 0, 0); \
    acc[1][0] = __builtin_amdgcn_mfma_f32_32x32x16_bf16(AF[1], BG[0], acc[1][0], 0, 0, 0); \
    acc[1][1] = __builtin_amdgcn_mfma_f32_32x32x16_bf16(AF[1], BG[1], acc[1][1], 0, 0, 0); \
    __builtin_amdgcn_s_setprio(0);                                             \
} while (0)

#define TILE(P, ST, TN, VMSTR) do {                                            \
    if (ST) STAGE((P) ^ 1, (TN) + 1);                                          \
    asm volatile("s_waitcnt vmcnt(" VMSTR ")" ::: "memory");                   \
    BARR();                                                                    \
    const uint32_t ab = ldsA32 + (P) * 32768 + aoff;                           \
    const uint32_t bb = ldsA32 + 65536 + (P) * 32768 + boff;                   \
    DSR(af0[0], ab + cof0); DSR(af0[1], ab + 4096 + cof0);                     \
    DSR(bg0[0], bb + cof0); DSR(bg0[1], bb + 4096 + cof0);                     \
    DSR(af1[0], ab + cof1); DSR(af1[1], ab + 4096 + cof1);                     \
    DSR(bg1[0], bb + cof1); DSR(bg1[1], bb + 4096 + cof1);                     \
    LGKM(4); SB0();                                                            \
    MM(af0, bg0);                            /* ks0 */                         \
    DSR(af0[0], ab + cof2); DSR(af0[1], ab + 4096 + cof2);                     \
    DSR(bg0[0], bb + cof2); DSR(bg0[1], bb + 4096 + cof2);                     \
    LGKM(4); SB0();                                                            \
    MM(af1, bg1);                            /* ks1 */                         \
    DSR(af1[0], ab + cof3); DSR(af1[1], ab + 4096 + cof3);                     \
    DSR(bg1[0], bb + cof3); DSR(bg1[1], bb + 4096 + cof3);                     \
    LGKM(4); SB0();                                                            \
    MM(af0, bg0);                            /* ks2 */                         \
    LGKM(0); SB0();                                                            \
    BARR();                                  /* all reads of buf P done */     \
    MM(af1, bg1);                            /* ks3 (regs only) */             \
} while (0)

    // ---- prologue: stage tile 0 into buf 0 ----
    STAGE(0, 0);
    TILE(0, 1, 0, "4");
    TILE(1, 1, 1, "4");
    TILE(0, 1, 2, "4");
    TILE(1, 1, 3, "4");
    TILE(0, 1, 4, "4");
    TILE(1, 1, 5, "4");
    TILE(0, 1, 6, "4");
    TILE(1, 0, 7, "0");

#undef DSR
#undef LGKM
#undef SB0
#undef BARR
#undef STAGE
#undef MM
#undef TILE

    // ---- epilogue: cosine scale, exp, row-reduce, one atomic per row ----
    // C/D 32x32 layout: col = lane&31, row = (reg&3) + 8*(reg>>2) + 4*(lane>>5)
    const float inj0 = inv_nj[col0 + wn * 64 + l31];
    const float inj1 = inv_nj[col0 + wn * 64 + 32 + l31];

    #pragma unroll
    for (int mi = 0; mi < 2; ++mi) {
        #pragma unroll
        for (int r = 0; r < 16; ++r) {
            const int row = row0 + wm * 64 + mi * 32 + (r & 3) + 8 * (r >> 2) + 4 * hh;
            const float ini = inv_ni[row];
            float s = __expf(acc[mi][0][r] * ini * inj0)
                    + __expf(acc[mi][1][r] * ini * inj1);
            s += __shfl_xor(s, 1, 64);
            s += __shfl_xor(s, 2, 64);
            s += __shfl_xor(s, 4, 64);
            s += __shfl_xor(s, 8, 64);
            s += __shfl_xor(s, 16, 64);
            if (l31 == 0)
                atomicAdd(&rowsum[row], s);
        }
    }
}

__global__ void finalize(const float* __restrict__ rowsum,
                         const float* __restrict__ diag,
                         float* __restrict__ out) {
    const float E1 = 2.7182818284590452f;  // exp(1/TAU)
    float acc = 0.0f;
    for (int i = threadIdx.x; i < NR; i += 256)
        acc += __logf(rowsum[i] - E1) - diag[i];
    #pragma unroll
    for (int m = 32; m >= 1; m >>= 1)
        acc += __shfl_xor(acc, m, 64);
    __shared__ float red[4];
    const int wave = threadIdx.x >> 6, lane = threadIdx.x & 63;
    if (lane == 0) red[wave] = acc;
    __syncthreads();
    if (threadIdx.x == 0)
        out[0] = (red[0] + red[1] + red[2] + red[3]) * (1.0f / NR);
}

extern "C" void kernel_launch(void* const* d_in, const int* in_sizes, int n_in,
                              void* d_out, int out_size, void* d_ws, size_t ws_size,
                              hipStream_t stream) {
    const float* xi = (const float*)d_in[0];
    const float* xj = (const float*)d_in[1];

    char* ws = (char*)d_ws;
    u16* xib = (u16*)ws;                                // 8 MB
    u16* xjb = xib + (size_t)NR * DIM;                  // 8 MB
    float* inv_ni = (float*)(xjb + (size_t)NR * DIM);   // 32 KB
    float* inv_nj = inv_ni + NR;
    float* diag   = inv_nj + NR;
    float* rowsum = diag + NR;

    prep_kernel<<<NR, 128, 0, stream>>>(xi, xj, xib, xjb, inv_ni, inv_nj, diag, rowsum);
    gemm_rowsum<<<(NR / BT) * (NR / BT), 1024, 0, stream>>>(xib, xjb, inv_ni, inv_nj, rowsum);
    finalize<<<1, 256, 0, stream>>>(rowsum, diag, (float*)d_out);
}

// Round 9
// 158.020 us; speedup vs baseline: 1.2183x; 1.2183x over previous
//
#include <hip/hip_runtime.h>
#include <stdint.h>

#define NR 8192
#define DIM 512
#define BT 128             // block tile M=N
#define BK 64              // K-tile (128 B rows, 8 x 16B chunks)
#define NT (DIM / BK)      // 8 K-tiles

typedef unsigned short u16;
typedef __attribute__((ext_vector_type(8))) __bf16 bf16x8;
typedef __attribute__((ext_vector_type(16))) float f32x16;

static __device__ __forceinline__ u16 f2bf(float f) {
    union { float f; uint32_t u; } v; v.f = f;
    uint32_t u = v.u;
    u += 0x7FFFu + ((u >> 16) & 1u);   // RNE
    return (u16)(u >> 16);
}

static __device__ __forceinline__ void gload_lds16(const void* g, void* l) {
    __builtin_amdgcn_global_load_lds(
        (__attribute__((address_space(1))) void*)(void*)g,
        (__attribute__((address_space(3))) void*)l,
        16, 0, 0);
}

// One block per row: reciprocal norms, exact fp32 diag term, fp32->bf16
// conversion, and zero rowsum for this call.
__global__ void prep_kernel(const float* __restrict__ xi, const float* __restrict__ xj,
                            u16* __restrict__ xib, u16* __restrict__ xjb,
                            float* __restrict__ inv_ni, float* __restrict__ inv_nj,
                            float* __restrict__ diag, float* __restrict__ rowsum) {
    const int row = blockIdx.x;
    const int t = threadIdx.x;                 // 128 threads, 4 elems each
    const float4 a = ((const float4*)(xi + (size_t)row * DIM))[t];
    const float4 b = ((const float4*)(xj + (size_t)row * DIM))[t];

    float ssi = a.x*a.x + a.y*a.y + a.z*a.z + a.w*a.w;
    float ssj = b.x*b.x + b.y*b.y + b.z*b.z + b.w*b.w;
    float dot = a.x*b.x + a.y*b.y + a.z*b.z + a.w*b.w;

    ushort4 av = { f2bf(a.x), f2bf(a.y), f2bf(a.z), f2bf(a.w) };
    ushort4 bv = { f2bf(b.x), f2bf(b.y), f2bf(b.z), f2bf(b.w) };
    ((ushort4*)(xib + (size_t)row * DIM))[t] = av;
    ((ushort4*)(xjb + (size_t)row * DIM))[t] = bv;

    #pragma unroll
    for (int m = 32; m >= 1; m >>= 1) {
        ssi += __shfl_xor(ssi, m, 64);
        ssj += __shfl_xor(ssj, m, 64);
        dot += __shfl_xor(dot, m, 64);
    }
    __shared__ float red[6];
    const int wave = t >> 6, lane = t & 63;
    if (lane == 0) { red[wave*3+0] = ssi; red[wave*3+1] = ssj; red[wave*3+2] = dot; }
    __syncthreads();
    if (t == 0) {
        float si = red[0] + red[3];
        float sj = red[1] + red[4];
        float d  = red[2] + red[5];
        float ini = rsqrtf(fmaxf(si, 1e-30f));
        float inj = rsqrtf(fmaxf(sj, 1e-30f));
        inv_ni[row] = ini;
        inv_nj[row] = inj;
        diag[row] = d * ini * inj;
        rowsum[row] = 0.0f;
    }
}

// Fused NT-GEMM + exp + row-sum. Round-7 structure (simple 2-barrier loop,
// TLP-hidden latency, conflict-free chunk swizzle) with 32x32x16 MFMA:
// 4 waves (2x2), wave tile 64x64 = 2x2 frags of 32x32, acc = 64 AGPR,
// operands 16 VGPR -> register-neutral vs round 7 (no spill risk).
__global__ __launch_bounds__(256, 4)
void gemm_rowsum(const u16* __restrict__ A, const u16* __restrict__ B,
                 const float* __restrict__ inv_ni, const float* __restrict__ inv_nj,
                 float* __restrict__ rowsum) {
    __shared__ __align__(16) u16 ldsA[BT * BK];   // 16 KB
    __shared__ __align__(16) u16 ldsB[BT * BK];   // 16 KB

    const int tid = threadIdx.x;
    // XCD-aware, L2-aware: xcd owns 8 row-panels; concurrent blocks/XCD
    // cover 8 row-panels x ~16 col-panels: A 1MB + B 2MB < 4MB per-XCD L2.
    const int orig = blockIdx.x;
    const int xcd = orig & 7, kidx = orig >> 3;   // kidx 0..511
    const int by = xcd * 8 + (kidx & 7);          // 0..63
    const int bx = kidx >> 3;                     // 0..63
    const int row0 = by * BT, col0 = bx * BT;

    // ---- staging: thread t -> part i row (i*32 + (t>>3)), phys chunk t&7 ----
    // LDS byte = i*4096 + tid*16 (linear); global logical chunk = phys ^ (row&7).
    const int st_row = tid >> 3;                        // 0..31
    const int st_lc  = (tid & 7) ^ (st_row & 7);        // logical 16B k-chunk
    const u16* gA = A + (size_t)(row0 + st_row) * DIM + st_lc * 8;
    const u16* gB = B + (size_t)(col0 + st_row) * DIM + st_lc * 8;
    char* const dA = (char*)ldsA + tid * 16;
    char* const dB = (char*)ldsB + tid * 16;

    // ---- fragment reads (32x32x16): lane -> row l&31, k-half l>>5 ----
    const int lane = tid & 63;
    const int l31 = lane & 31, hh = lane >> 5, sw = l31 & 7;
    const int wid = tid >> 6;
    const int wm = wid >> 1, wn = wid & 1;              // 2x2 waves, 64x64 tile
    // frag fi (0/1): row = w*64 + fi*32 + l31 (row&7 == l31&7);
    // k-step ks (0..3): logical chunk = ks*2 + hh; phys byte = (logical^sw)*16
    const char* const aR = (const char*)ldsA + (wm * 64 + l31) * 128;
    const char* const bR = (const char*)ldsB + (wn * 64 + l31) * 128;

    f32x16 acc[2][2] = {};

    #pragma unroll 1
    for (int t = 0; t < NT; ++t) {
        if (t) __syncthreads();               // prev tile's reads complete
        #pragma unroll
        for (int i = 0; i < 4; ++i) {         // 8 x global_load_lds_dwordx4
            gload_lds16(gA + t * BK + i * 32 * DIM, dA + i * 4096);
            gload_lds16(gB + t * BK + i * 32 * DIM, dB + i * 4096);
        }
        __syncthreads();                      // drains vmcnt; TLP fills stall

        #pragma unroll
        for (int ks = 0; ks < 4; ++ks) {
            const int cb = ((ks * 2 + hh) ^ sw) * 16;
            bf16x8 a0 = *(const bf16x8*)(aR + cb);
            bf16x8 a1 = *(const bf16x8*)(aR + 4096 + cb);
            bf16x8 b0 = *(const bf16x8*)(bR + cb);
            bf16x8 b1 = *(const bf16x8*)(bR + 4096 + cb);
            acc[0][0] = __builtin_amdgcn_mfma_f32_32x32x16_bf16(a0, b0, acc[0][0], 0, 0, 0);
            acc[0][1] = __builtin_amdgcn_mfma_f32_32x32x16_bf16(a0, b1, acc[0][1], 0, 0, 0);
            acc[1][0] = __builtin_amdgcn_mfma_f32_32x32x16_bf16(a1, b0, acc[1][0], 0, 0, 0);
            acc[1][1] = __builtin_amdgcn_mfma_f32_32x32x16_bf16(a1, b1, acc[1][1], 0, 0, 0);
        }
    }

    // ---- epilogue: cosine scale, exp, row-reduce, one atomic per row ----
    // C/D 32x32 layout: col = lane&31, row = (reg&3) + 8*(reg>>2) + 4*(lane>>5)
    const float inj0 = inv_nj[col0 + wn * 64 + l31];
    const float inj1 = inv_nj[col0 + wn * 64 + 32 + l31];

    #pragma unroll
    for (int mi = 0; mi < 2; ++mi) {
        #pragma unroll
        for (int r = 0; r < 16; ++r) {
            const int row = row0 + wm * 64 + mi * 32 + (r & 3) + 8 * (r >> 2) + 4 * hh;
            const float ini = inv_ni[row];
            float s = __expf(acc[mi][0][r] * ini * inj0)
                    + __expf(acc[mi][1][r] * ini * inj1);
            s += __shfl_xor(s, 1, 64);
            s += __shfl_xor(s, 2, 64);
            s += __shfl_xor(s, 4, 64);
            s += __shfl_xor(s, 8, 64);
            s += __shfl_xor(s, 16, 64);
            if (l31 == 0)
                atomicAdd(&rowsum[row], s);
        }
    }
}

__global__ void finalize(const float* __restrict__ rowsum,
                         const float* __restrict__ diag,
                         float* __restrict__ out) {
    const float E1 = 2.7182818284590452f;  // exp(1/TAU)
    float acc = 0.0f;
    for (int i = threadIdx.x; i < NR; i += 256)
        acc += __logf(rowsum[i] - E1) - diag[i];
    #pragma unroll
    for (int m = 32; m >= 1; m >>= 1)
        acc += __shfl_xor(acc, m, 64);
    __shared__ float red[4];
    const int wave = threadIdx.x >> 6, lane = threadIdx.x & 63;
    if (lane == 0) red[wave] = acc;
    __syncthreads();
    if (threadIdx.x == 0)
        out[0] = (red[0] + red[1] + red[2] + red[3]) * (1.0f / NR);
}

extern "C" void kernel_launch(void* const* d_in, const int* in_sizes, int n_in,
                              void* d_out, int out_size, void* d_ws, size_t ws_size,
                              hipStream_t stream) {
    const float* xi = (const float*)d_in[0];
    const float* xj = (const float*)d_in[1];

    char* ws = (char*)d_ws;
    u16* xib = (u16*)ws;                                // 8 MB
    u16* xjb = xib + (size_t)NR * DIM;                  // 8 MB
    float* inv_ni = (float*)(xjb + (size_t)NR * DIM);   // 32 KB
    float* inv_nj = inv_ni + NR;
    float* diag   = inv_nj + NR;
    float* rowsum = diag + NR;

    prep_kernel<<<NR, 128, 0, stream>>>(xi, xj, xib, xjb, inv_ni, inv_nj, diag, rowsum);
    gemm_rowsum<<<(NR / BT) * (NR / BT), 256, 0, stream>>>(xib, xjb, inv_ni, inv_nj, rowsum);
    finalize<<<1, 256, 0, stream>>>(rowsum, diag, (float*)d_out);
}